// Round 5
// baseline (62.742 us; speedup 1.0000x reference)
//
#include <hip/hip_runtime.h>
#include <stdint.h>
#include <math.h>

// EmptyImageDetector: per-image [32,3,512,512] fp32
//   out[0..31]  = distinct (r,g,b) pixel-color count (linear-counting estimate)
//   out[32..63] = mean over channels of unbiased (ddof=1) variance over pixels
//   out[64..95] = mean over (C,H,W)
//
// R5: SINGLE fused kernel. 256 blocks = 32 images x 8 pixel-ranges.
//  - each block: stream its 1/8 of the image once (float4), f64 sum/sumsq,
//    hash -> 2^17-bit LDS bitmap (LDS atomicOr, no-return);
//  - dump bitmap (16 KiB = exactly 1 uint4/thread) + f64 partials to ws;
//  - release fence + device atomicAdd(arrive[img]); the 8th arriver per image
//    acquire-fences, ORs the 8 bitmaps (1 uint4/thread/bitmap), popcounts the
//    union, inverts the linear-counting estimator (S=2^17, lambda=2,
//    std ~758 = 0.29% of N vs 2% threshold), reduces partials, writes the
//    image's 3 outputs. Last-arriver never waits -> deadlock-free regardless
//    of residency; fences handle cross-XCD L2 non-coherence (G16).
//
// ws layout:
//   [0, 4 MiB)        : uint32 bitmaps[256][4096]
//   [4 MiB, +12 KiB)  : double partials[256][6]
//   [+12 KiB, +128 B) : unsigned arrive[32]   (memset to 0 each call)

#define TPB 1024
#define P 8
#define LOG2_BITS 17
#define NWORDS (1 << (LOG2_BITS - 5))     // 4096 uint32 words = 16 KiB

__device__ __forceinline__ uint32_t hash3(uint32_t r, uint32_t g, uint32_t b) {
    uint32_t u = r * 0x9E3779B9u + g * 0x85EBCA6Bu + b * 0xC2B2AE35u;
    u ^= u >> 16; u *= 0x7FEB352Du;
    u ^= u >> 15; u *= 0x846CA68Bu;
    u ^= u >> 16;
    return u;
}

__global__ __launch_bounds__(TPB) void fused(
    const float* __restrict__ in,
    uint32_t* __restrict__ bitmaps,
    double* __restrict__ partials,
    unsigned* __restrict__ arrive,
    float* __restrict__ out,
    int N)
{
    __shared__ uint32_t bitmap[NWORDS];
    __shared__ double   reds[TPB / 64][6];
    __shared__ unsigned redc[TPB / 64];
    __shared__ int      tail_flag;

    const int b   = blockIdx.x;           // 0..255
    const int img = b >> 3;
    const int sub = b & 7;

    #pragma unroll
    for (int w = threadIdx.x; w < NWORDS; w += TPB) bitmap[w] = 0u;  // 4 iters
    __syncthreads();

    const float* base = in + (size_t)img * 3u * (size_t)N;
    const float4* r4 = (const float4*)(base);
    const float4* g4 = (const float4*)(base + N);
    const float4* b4 = (const float4*)(base + 2 * N);

    const int f4_per_blk = (N >> 2) / P;  // 8192
    const int off = sub * f4_per_blk;

    double s0 = 0, s1 = 0, s2 = 0, q0 = 0, q1 = 0, q2 = 0;

    for (int i = threadIdx.x; i < f4_per_blk; i += TPB) {  // 8 iterations
        const int idx = off + i;
        float4 r  = r4[idx];
        float4 g  = g4[idx];
        float4 bb = b4[idx];
        float fr[4] = {r.x, r.y, r.z, r.w};
        float fg[4] = {g.x, g.y, g.z, g.w};
        float fb[4] = {bb.x, bb.y, bb.z, bb.w};
        #pragma unroll
        for (int k = 0; k < 4; k++) {
            s0 += (double)fr[k]; q0 += (double)fr[k] * (double)fr[k];
            s1 += (double)fg[k]; q1 += (double)fg[k] * (double)fg[k];
            s2 += (double)fb[k]; q2 += (double)fb[k] * (double)fb[k];
            uint32_t h = hash3(__float_as_uint(fr[k]), __float_as_uint(fg[k]),
                               __float_as_uint(fb[k])) & ((1u << LOG2_BITS) - 1u);
            atomicOr(&bitmap[h >> 5], 1u << (h & 31u));   // LDS ds_or, no return
        }
    }

    // block-reduce the f64 partial sums (no LDS use yet -> bitmap untouched)
    for (int o = 32; o > 0; o >>= 1) {
        s0 += __shfl_down(s0, o); s1 += __shfl_down(s1, o); s2 += __shfl_down(s2, o);
        q0 += __shfl_down(q0, o); q1 += __shfl_down(q1, o); q2 += __shfl_down(q2, o);
    }
    const int wave = threadIdx.x >> 6;
    const int lane = threadIdx.x & 63;
    if (lane == 0) {
        reds[wave][0] = s0; reds[wave][1] = s1; reds[wave][2] = s2;
        reds[wave][3] = q0; reds[wave][4] = q1; reds[wave][5] = q2;
    }
    __syncthreads();   // orders bitmap atomicOrs AND reds writes

    // dump bitmap: NWORDS/4 == TPB -> exactly one uint4 per thread
    ((uint4*)(bitmaps + (size_t)b * NWORDS))[threadIdx.x] =
        ((const uint4*)bitmap)[threadIdx.x];

    if (threadIdx.x == 0) {
        double acc[6] = {0, 0, 0, 0, 0, 0};
        #pragma unroll
        for (int w = 0; w < TPB / 64; w++)
            #pragma unroll
            for (int j = 0; j < 6; j++) acc[j] += reds[w][j];
        #pragma unroll
        for (int j = 0; j < 6; j++) partials[b * 6 + j] = acc[j];
    }

    __syncthreads();   // drains each thread's outstanding stores (vmcnt) too
    if (threadIdx.x == 0) {
        __threadfence();                                  // release: L2 writeback
        tail_flag = (atomicAdd(&arrive[img], 1u) == P - 1u);
    }
    __syncthreads();
    if (!tail_flag) return;

    // ---- tail: this block is the 8th arriver for its image ----
    __threadfence();   // acquire: invalidate L1/L2 before reading peers' data

    const uint32_t* bm = bitmaps + (size_t)img * P * NWORDS;
    uint4 a = ((const uint4*)bm)[threadIdx.x];
    #pragma unroll
    for (int p = 1; p < P; p++) {
        uint4 v = ((const uint4*)(bm + (size_t)p * NWORDS))[threadIdx.x];
        a.x |= v.x; a.y |= v.y; a.z |= v.z; a.w |= v.w;
    }
    unsigned t = __popc(a.x) + __popc(a.y) + __popc(a.z) + __popc(a.w);
    for (int o = 32; o > 0; o >>= 1) t += __shfl_down(t, o);
    if (lane == 0) redc[wave] = t;
    __syncthreads();

    if (threadIdx.x == 0) {
        unsigned tot = 0;
        #pragma unroll
        for (int w = 0; w < TPB / 64; w++) tot += redc[w];

        const double S = (double)(1u << LOG2_BITS);
        double tt = (double)tot;
        if (tt > S - 1.0) tt = S - 1.0;
        out[img] = (float)(-S * log1p(-tt / S));          // linear counting

        double acc[6] = {0, 0, 0, 0, 0, 0};
        for (int p = 0; p < P; p++)
            #pragma unroll
            for (int j = 0; j < 6; j++) acc[j] += partials[(img * P + p) * 6 + j];

        const double dN = (double)N;
        double v = 0.0;
        #pragma unroll
        for (int c = 0; c < 3; c++)
            v += (acc[3 + c] - acc[c] * acc[c] / dN) / (dN - 1.0);
        out[32 + img] = (float)(v / 3.0);
        out[64 + img] = (float)((acc[0] + acc[1] + acc[2]) / (3.0 * dN));
    }
}

extern "C" void kernel_launch(void* const* d_in, const int* in_sizes, int n_in,
                              void* d_out, int out_size, void* d_ws, size_t ws_size,
                              hipStream_t stream) {
    const float* in = (const float*)d_in[0];
    float* out = (float*)d_out;

    const int B = 32, C = 3;
    const int N = in_sizes[0] / (B * C);   // 262144

    uint32_t* bitmaps  = (uint32_t*)d_ws;
    double*   partials = (double*)((char*)d_ws + (size_t)B * P * NWORDS * sizeof(uint32_t));
    unsigned* arrive   = (unsigned*)((char*)partials + (size_t)B * P * 6 * sizeof(double));

    hipMemsetAsync(arrive, 0, B * sizeof(unsigned), stream);
    fused<<<dim3(B * P), dim3(TPB), 0, stream>>>(in, bitmaps, partials, arrive, out, N);
}

// Round 6
// 28.514 us; speedup vs baseline: 2.2004x; 2.2004x over previous
//
#include <hip/hip_runtime.h>
#include <stdint.h>
#include <math.h>

// EmptyImageDetector: per-image [32,3,512,512] fp32
//   out[0..31]  = distinct (r,g,b) pixel-color count (linear-counting estimate)
//   out[32..63] = mean over channels of unbiased (ddof=1) variance over pixels
//   out[64..95] = mean over (C,H,W)
//
// R6: back to kernel-boundary coherence (R5's intra-kernel threadfence fusion
// cost 288 L2 writeback/invalidate ops and regressed 2x).
//   K1 (256 blocks = 32 img x 8 ranges): stream pixels once (float4), f64
//      sum/sumsq, hash -> 2^17-bit LDS bitmap (ds_or no-return); dump bitmap
//      (exactly 1 uint4/thread) + f64 partials.
//   K2 (32 blocks, one per image): OR the 8 bitmaps (1 uint4/thread each),
//      popcount union, invert linear-counting estimator (S=2^17, lambda=2,
//      std ~758 = 0.29% of N vs 2% threshold; measured absmax 2048 in R5),
//      reduce partials, write the image's 3 outputs.
// No global atomics, no memsets (every ws byte written before read).
//
// ws layout:
//   [0, 4 MiB)       : uint32 bitmaps[256][4096]
//   [4 MiB, +12 KiB) : double partials[256][6]

#define TPB 1024
#define P 8
#define LOG2_BITS 17
#define NWORDS (1 << (LOG2_BITS - 5))     // 4096 uint32 words = 16 KiB

__device__ __forceinline__ uint32_t hash3(uint32_t r, uint32_t g, uint32_t b) {
    uint32_t u = r * 0x9E3779B9u + g * 0x85EBCA6Bu + b * 0xC2B2AE35u;
    u ^= u >> 16; u *= 0x7FEB352Du;
    u ^= u >> 15; u *= 0x846CA68Bu;
    u ^= u >> 16;
    return u;
}

__global__ __launch_bounds__(TPB) void pass1(
    const float* __restrict__ in,
    uint32_t* __restrict__ bitmaps,
    double* __restrict__ partials,
    int N)
{
    __shared__ uint32_t bitmap[NWORDS];
    __shared__ double   reds[TPB / 64][6];

    const int b   = blockIdx.x;           // 0..255
    const int img = b >> 3;
    const int sub = b & 7;

    #pragma unroll
    for (int w = threadIdx.x; w < NWORDS; w += TPB) bitmap[w] = 0u;  // 4 iters
    __syncthreads();

    const float* base = in + (size_t)img * 3u * (size_t)N;
    const float4* r4 = (const float4*)(base);
    const float4* g4 = (const float4*)(base + N);
    const float4* b4 = (const float4*)(base + 2 * N);

    const int f4_per_blk = (N >> 2) / P;  // 8192
    const int off = sub * f4_per_blk;

    double s0 = 0, s1 = 0, s2 = 0, q0 = 0, q1 = 0, q2 = 0;

    #pragma unroll 2
    for (int i = threadIdx.x; i < f4_per_blk; i += TPB) {  // 8 iterations
        const int idx = off + i;
        float4 r  = r4[idx];
        float4 g  = g4[idx];
        float4 bb = b4[idx];
        float fr[4] = {r.x, r.y, r.z, r.w};
        float fg[4] = {g.x, g.y, g.z, g.w};
        float fb[4] = {bb.x, bb.y, bb.z, bb.w};
        #pragma unroll
        for (int k = 0; k < 4; k++) {
            s0 += (double)fr[k]; q0 += (double)fr[k] * (double)fr[k];
            s1 += (double)fg[k]; q1 += (double)fg[k] * (double)fg[k];
            s2 += (double)fb[k]; q2 += (double)fb[k] * (double)fb[k];
            uint32_t h = hash3(__float_as_uint(fr[k]), __float_as_uint(fg[k]),
                               __float_as_uint(fb[k])) & ((1u << LOG2_BITS) - 1u);
            atomicOr(&bitmap[h >> 5], 1u << (h & 31u));   // LDS ds_or, no return
        }
    }

    // block-reduce the f64 partial sums
    for (int o = 32; o > 0; o >>= 1) {
        s0 += __shfl_down(s0, o); s1 += __shfl_down(s1, o); s2 += __shfl_down(s2, o);
        q0 += __shfl_down(q0, o); q1 += __shfl_down(q1, o); q2 += __shfl_down(q2, o);
    }
    const int wave = threadIdx.x >> 6;
    const int lane = threadIdx.x & 63;
    if (lane == 0) {
        reds[wave][0] = s0; reds[wave][1] = s1; reds[wave][2] = s2;
        reds[wave][3] = q0; reds[wave][4] = q1; reds[wave][5] = q2;
    }
    __syncthreads();   // orders bitmap atomicOrs AND reds writes

    // dump bitmap: NWORDS/4 == TPB -> exactly one uint4 per thread
    ((uint4*)(bitmaps + (size_t)b * NWORDS))[threadIdx.x] =
        ((const uint4*)bitmap)[threadIdx.x];

    if (threadIdx.x == 0) {
        double acc[6] = {0, 0, 0, 0, 0, 0};
        #pragma unroll
        for (int w = 0; w < TPB / 64; w++)
            #pragma unroll
            for (int j = 0; j < 6; j++) acc[j] += reds[w][j];
        #pragma unroll
        for (int j = 0; j < 6; j++) partials[b * 6 + j] = acc[j];
    }
}

// 32 blocks, one per image: union + popcount + estimator + variance/brightness.
__global__ __launch_bounds__(TPB) void pass2(
    const uint32_t* __restrict__ bitmaps,
    const double* __restrict__ partials,
    float* __restrict__ out, int N)
{
    const int img = blockIdx.x;
    const uint32_t* bm = bitmaps + (size_t)img * P * NWORDS;

    uint4 a = ((const uint4*)bm)[threadIdx.x];      // NWORDS/4 == TPB
    #pragma unroll
    for (int p = 1; p < P; p++) {
        uint4 v = ((const uint4*)(bm + (size_t)p * NWORDS))[threadIdx.x];
        a.x |= v.x; a.y |= v.y; a.z |= v.z; a.w |= v.w;
    }
    unsigned t = __popc(a.x) + __popc(a.y) + __popc(a.z) + __popc(a.w);

    for (int o = 32; o > 0; o >>= 1) t += __shfl_down(t, o);
    __shared__ unsigned redc[TPB / 64];
    const int wave = threadIdx.x >> 6;
    const int lane = threadIdx.x & 63;
    if (lane == 0) redc[wave] = t;
    __syncthreads();

    if (threadIdx.x == 0) {
        unsigned tot = 0;
        #pragma unroll
        for (int w = 0; w < TPB / 64; w++) tot += redc[w];

        const double S = (double)(1u << LOG2_BITS);
        double tt = (double)tot;
        if (tt > S - 1.0) tt = S - 1.0;
        out[img] = (float)(-S * log1p(-tt / S));    // linear-counting inversion

        double acc[6] = {0, 0, 0, 0, 0, 0};
        for (int p = 0; p < P; p++)
            #pragma unroll
            for (int j = 0; j < 6; j++) acc[j] += partials[(img * P + p) * 6 + j];

        const double dN = (double)N;
        double v = 0.0;
        #pragma unroll
        for (int c = 0; c < 3; c++)
            v += (acc[3 + c] - acc[c] * acc[c] / dN) / (dN - 1.0);
        out[32 + img] = (float)(v / 3.0);
        out[64 + img] = (float)((acc[0] + acc[1] + acc[2]) / (3.0 * dN));
    }
}

extern "C" void kernel_launch(void* const* d_in, const int* in_sizes, int n_in,
                              void* d_out, int out_size, void* d_ws, size_t ws_size,
                              hipStream_t stream) {
    const float* in = (const float*)d_in[0];
    float* out = (float*)d_out;

    const int B = 32, C = 3;
    const int N = in_sizes[0] / (B * C);   // 262144

    uint32_t* bitmaps  = (uint32_t*)d_ws;
    double*   partials = (double*)((char*)d_ws + (size_t)B * P * NWORDS * sizeof(uint32_t));

    pass1<<<dim3(B * P), dim3(TPB), 0, stream>>>(in, bitmaps, partials, N);
    pass2<<<dim3(B), dim3(TPB), 0, stream>>>(bitmaps, partials, out, N);
}

// Round 7
// 27.420 us; speedup vs baseline: 2.2882x; 1.0399x over previous
//
#include <hip/hip_runtime.h>
#include <stdint.h>
#include <math.h>

// EmptyImageDetector: per-image [32,3,512,512] fp32
//   out[0..31]  = distinct (r,g,b) pixel-color count (linear-counting estimate)
//   out[32..63] = mean over channels of unbiased (ddof=1) variance over pixels
//   out[64..95] = mean over (C,H,W)
//
// R7: keep R6's two-pass launch-boundary structure (R5 showed intra-kernel
// fences cost 2x). Cut quarter-rate-pipe work out of the hot loop:
//   - f32 accumulation per thread (partials <= 64; error ~1e-5 rel, final
//     combine in f64; variance threshold is 2% -> 4 orders of margin)
//   - xor-rotate channel combine + 2-mul lowbias32 finalizer (was 5 muls;
//     v_mul_lo_u32 is quarter-rate)
//   - P=4: 128 blocks x 16 iters; dump 2 MB (was 4), pass2 unions 4 bitmaps.
//     128 CUs need only 55 GB/s each to saturate HBM.
// Union bitmap: S=2^17 bits, lambda=2, std ~758 (measured absmax 2048 = 0.78%
// of N vs 2% threshold).
//
// ws layout:
//   [0, 2 MiB)       : uint32 bitmaps[128][4096]
//   [2 MiB, +6 KiB)  : double partials[128][6]

#define TPB 1024
#define P 4
#define LOG2_BITS 17
#define NWORDS (1 << (LOG2_BITS - 5))     // 4096 uint32 words = 16 KiB

__device__ __forceinline__ uint32_t hash3(uint32_t r, uint32_t g, uint32_t b) {
    uint32_t u = r ^ ((g << 11) | (g >> 21)) ^ ((b << 22) | (b >> 10));
    u ^= u >> 16; u *= 0x7FEB352Du;      // lowbias32 finalizer (2 muls)
    u ^= u >> 15; u *= 0x846CA68Bu;
    u ^= u >> 16;
    return u;
}

__global__ __launch_bounds__(TPB) void pass1(
    const float* __restrict__ in,
    uint32_t* __restrict__ bitmaps,
    double* __restrict__ partials,
    int N)
{
    __shared__ uint32_t bitmap[NWORDS];
    __shared__ double   reds[TPB / 64][6];

    const int b   = blockIdx.x;           // 0..127
    const int img = b >> 2;
    const int sub = b & 3;

    #pragma unroll
    for (int w = threadIdx.x; w < NWORDS; w += TPB) bitmap[w] = 0u;  // 4 iters
    __syncthreads();

    const float* base = in + (size_t)img * 3u * (size_t)N;
    const float4* r4 = (const float4*)(base);
    const float4* g4 = (const float4*)(base + N);
    const float4* b4 = (const float4*)(base + 2 * N);

    const int f4_per_blk = (N >> 2) / P;  // 16384
    const int off = sub * f4_per_blk;

    float s0 = 0.f, s1 = 0.f, s2 = 0.f, q0 = 0.f, q1 = 0.f, q2 = 0.f;

    #pragma unroll 4
    for (int i = threadIdx.x; i < f4_per_blk; i += TPB) {  // 16 iterations
        const int idx = off + i;
        float4 r  = r4[idx];
        float4 g  = g4[idx];
        float4 bb = b4[idx];
        float fr[4] = {r.x, r.y, r.z, r.w};
        float fg[4] = {g.x, g.y, g.z, g.w};
        float fb[4] = {bb.x, bb.y, bb.z, bb.w};
        #pragma unroll
        for (int k = 0; k < 4; k++) {
            s0 += fr[k]; q0 = fmaf(fr[k], fr[k], q0);
            s1 += fg[k]; q1 = fmaf(fg[k], fg[k], q1);
            s2 += fb[k]; q2 = fmaf(fb[k], fb[k], q2);
            uint32_t h = hash3(__float_as_uint(fr[k]), __float_as_uint(fg[k]),
                               __float_as_uint(fb[k])) & ((1u << LOG2_BITS) - 1u);
            atomicOr(&bitmap[h >> 5], 1u << (h & 31u));   // LDS ds_or, no return
        }
    }

    // block-reduce partial sums in f64 (tail only; hot loop stayed f32)
    double d0 = s0, d1 = s1, d2 = s2, e0 = q0, e1 = q1, e2 = q2;
    for (int o = 32; o > 0; o >>= 1) {
        d0 += __shfl_down(d0, o); d1 += __shfl_down(d1, o); d2 += __shfl_down(d2, o);
        e0 += __shfl_down(e0, o); e1 += __shfl_down(e1, o); e2 += __shfl_down(e2, o);
    }
    const int wave = threadIdx.x >> 6;
    const int lane = threadIdx.x & 63;
    if (lane == 0) {
        reds[wave][0] = d0; reds[wave][1] = d1; reds[wave][2] = d2;
        reds[wave][3] = e0; reds[wave][4] = e1; reds[wave][5] = e2;
    }
    __syncthreads();   // orders bitmap atomicOrs AND reds writes

    // dump bitmap: NWORDS/4 == TPB -> exactly one uint4 per thread
    ((uint4*)(bitmaps + (size_t)b * NWORDS))[threadIdx.x] =
        ((const uint4*)bitmap)[threadIdx.x];

    if (threadIdx.x == 0) {
        double acc[6] = {0, 0, 0, 0, 0, 0};
        #pragma unroll
        for (int w = 0; w < TPB / 64; w++)
            #pragma unroll
            for (int j = 0; j < 6; j++) acc[j] += reds[w][j];
        #pragma unroll
        for (int j = 0; j < 6; j++) partials[b * 6 + j] = acc[j];
    }
}

// 32 blocks, one per image: union + popcount + estimator + variance/brightness.
__global__ __launch_bounds__(TPB) void pass2(
    const uint32_t* __restrict__ bitmaps,
    const double* __restrict__ partials,
    float* __restrict__ out, int N)
{
    const int img = blockIdx.x;
    const uint32_t* bm = bitmaps + (size_t)img * P * NWORDS;

    uint4 a = ((const uint4*)bm)[threadIdx.x];      // NWORDS/4 == TPB
    #pragma unroll
    for (int p = 1; p < P; p++) {
        uint4 v = ((const uint4*)(bm + (size_t)p * NWORDS))[threadIdx.x];
        a.x |= v.x; a.y |= v.y; a.z |= v.z; a.w |= v.w;
    }
    unsigned t = __popc(a.x) + __popc(a.y) + __popc(a.z) + __popc(a.w);

    for (int o = 32; o > 0; o >>= 1) t += __shfl_down(t, o);
    __shared__ unsigned redc[TPB / 64];
    const int wave = threadIdx.x >> 6;
    const int lane = threadIdx.x & 63;
    if (lane == 0) redc[wave] = t;
    __syncthreads();

    if (threadIdx.x == 0) {
        unsigned tot = 0;
        #pragma unroll
        for (int w = 0; w < TPB / 64; w++) tot += redc[w];

        const double S = (double)(1u << LOG2_BITS);
        double tt = (double)tot;
        if (tt > S - 1.0) tt = S - 1.0;
        out[img] = (float)(-S * log1p(-tt / S));    // linear-counting inversion

        double acc[6] = {0, 0, 0, 0, 0, 0};
        for (int p = 0; p < P; p++)
            #pragma unroll
            for (int j = 0; j < 6; j++) acc[j] += partials[(img * P + p) * 6 + j];

        const double dN = (double)N;
        double v = 0.0;
        #pragma unroll
        for (int c = 0; c < 3; c++)
            v += (acc[3 + c] - acc[c] * acc[c] / dN) / (dN - 1.0);
        out[32 + img] = (float)(v / 3.0);
        out[64 + img] = (float)((acc[0] + acc[1] + acc[2]) / (3.0 * dN));
    }
}

extern "C" void kernel_launch(void* const* d_in, const int* in_sizes, int n_in,
                              void* d_out, int out_size, void* d_ws, size_t ws_size,
                              hipStream_t stream) {
    const float* in = (const float*)d_in[0];
    float* out = (float*)d_out;

    const int B = 32, C = 3;
    const int N = in_sizes[0] / (B * C);   // 262144

    uint32_t* bitmaps  = (uint32_t*)d_ws;
    double*   partials = (double*)((char*)d_ws + (size_t)B * P * NWORDS * sizeof(uint32_t));

    pass1<<<dim3(B * P), dim3(TPB), 0, stream>>>(in, bitmaps, partials, N);
    pass2<<<dim3(B), dim3(TPB), 0, stream>>>(bitmaps, partials, out, N);
}